// Round 11
// baseline (153.645 us; speedup 1.0000x reference)
//
#include <hip/hip_runtime.h>

#define NEG_INF (-3.402823466e+38f)

constexpr int Bc = 8, Cc = 512, Hc = 8, Dc = 64, Nc = 1024;
constexpr size_t QSZ = (size_t)Bc * Hc * Nc * Dc;  // 4,194,304 elements
constexpr size_t XTSZ = (size_t)8192 * 512;        // = QSZ
constexpr size_t WTSZ = (size_t)1536 * 512;

typedef __attribute__((ext_vector_type(8))) short short8;
typedef __attribute__((ext_vector_type(4))) float f32x4;
typedef unsigned short ushort_t;
typedef unsigned int uint_t;

// ------------------------------------------------------------ bf16 helpers
__device__ __forceinline__ ushort_t f2bf(float x) {
  uint_t u = __float_as_uint(x);
  u += 0x7FFFu + ((u >> 16) & 1u);  // round-to-nearest-even
  return (ushort_t)(u >> 16);
}
__device__ __forceinline__ float bf2f(ushort_t h) {
  return __uint_as_float(((uint_t)h) << 16);
}

// ---------------------------------------------------------------- zero output
__global__ void zero_out_k(float* __restrict__ o) {
  int i = blockIdx.x * 256 + threadIdx.x;
  if (i < Bc * Cc) o[i] = 0.f;
}

// ------------------------------------------------- transpose+split x -> xt
__global__ __launch_bounds__(256) void conv_x(const float* __restrict__ x,
                                              ushort_t* __restrict__ xh,
                                              ushort_t* __restrict__ xl) {
  __shared__ float t[64][65];
  const int b = blockIdx.z, c0 = blockIdx.y * 64, n0 = blockIdx.x * 64;
  const int tid = threadIdx.x;
  const int lc = tid & 63, lr = tid >> 6;
#pragma unroll
  for (int i = 0; i < 16; ++i) {
    int cc = lr + i * 4;
    t[cc][lc] = x[((size_t)(b * 512 + c0 + cc)) * 1024 + n0 + lc];
  }
  __syncthreads();
#pragma unroll
  for (int i = 0; i < 16; ++i) {
    int nn = lr + i * 4;
    float v = t[lc][nn];  // = x[b][c0+lc][n0+nn]
    ushort_t h = f2bf(v);
    ushort_t lo = f2bf(v - bf2f(h));
    size_t o = ((size_t)(b * 1024 + n0 + nn)) * 512 + c0 + lc;
    xh[o] = h;
    xl[o] = lo;
  }
}

// ------------------------------------------------- transpose+split W -> wt
__global__ __launch_bounds__(256) void conv_w(const float* __restrict__ wq,
                                              ushort_t* __restrict__ wh,
                                              ushort_t* __restrict__ wl) {
  __shared__ float t[64][65];
  const int c0 = blockIdx.y * 64, j0 = blockIdx.x * 64;
  const int tid = threadIdx.x;
  const int lj = tid & 63, lr = tid >> 6;
#pragma unroll
  for (int i = 0; i < 16; ++i) {
    int cc = lr + i * 4;
    t[cc][lj] = wq[(size_t)(c0 + cc) * 1536 + j0 + lj];
  }
  __syncthreads();
#pragma unroll
  for (int i = 0; i < 16; ++i) {
    int jj = lr + i * 4;
    float v = t[lj][jj];  // = W[c0+lj][j0+jj]
    ushort_t h = f2bf(v);
    ushort_t lo = f2bf(v - bf2f(h));
    size_t o = (size_t)(j0 + jj) * 512 + c0 + lj;
    wh[o] = h;
    wl[o] = lo;
  }
}

// ------------------------------------------------------ async stage helper
__device__ __forceinline__ void stage_tile(ushort_t* lds, const ushort_t* g,
                                           int tid) {
  typedef const __attribute__((address_space(1))) unsigned int GU;
  typedef __attribute__((address_space(3))) unsigned int LU;
  {
    int l = tid, r = l >> 2, c = (l & 3) * 8;
    __builtin_amdgcn_global_load_lds((GU*)(g + (size_t)r * 512 + c),
                                     (LU*)(lds + (size_t)l * 8), 16, 0, 0);
  }
  {
    int l = tid + 256, r = l >> 2, c = (l & 3) * 8;
    __builtin_amdgcn_global_load_lds((GU*)(g + (size_t)r * 512 + c),
                                     (LU*)(lds + (size_t)l * 8), 16, 0, 0);
  }
}

// ---------------------------------------------------------------- QKV GEMM
// Epilogue: v fp32; q/k as bf16-hi (for the MFMA prefilter scan) + full
// fp32 copy (for exact rescore).
__global__ __launch_bounds__(256) void qkv_gemm_mfma(
    const ushort_t* __restrict__ xth, const ushort_t* __restrict__ xtl,
    const ushort_t* __restrict__ wth, const ushort_t* __restrict__ wtl,
    const float* __restrict__ bias, float* __restrict__ vbuf,
    float* __restrict__ kf, float* __restrict__ qf,
    ushort_t* __restrict__ khi, ushort_t* __restrict__ qhi) {
  __shared__ __align__(16) ushort_t Ah[128 * 32];
  __shared__ __align__(16) ushort_t Al[128 * 32];
  __shared__ __align__(16) ushort_t Bh[128 * 32];
  __shared__ __align__(16) ushort_t Bl[128 * 32];

  const int m0 = blockIdx.x * 128, j0 = blockIdx.y * 128;
  const int tid = threadIdx.x;
  const int w = tid >> 6, l = tid & 63;
  const int lr = l & 15, lg = l >> 4;
  const int wr = w >> 1, wc = w & 1;

  f32x4 acc[4][4];
#pragma unroll
  for (int i = 0; i < 4; ++i)
#pragma unroll
    for (int j = 0; j < 4; ++j) acc[i][j] = (f32x4){0.f, 0.f, 0.f, 0.f};

  const ushort_t* xa = xth + (size_t)m0 * 512;
  const ushort_t* xb = xtl + (size_t)m0 * 512;
  const ushort_t* wa = wth + (size_t)j0 * 512;
  const ushort_t* wb = wtl + (size_t)j0 * 512;

  for (int s = 0; s < 16; ++s) {
    const int k0 = s * 32;
    stage_tile(Ah, xa + k0, tid);
    stage_tile(Al, xb + k0, tid);
    stage_tile(Bh, wa + k0, tid);
    stage_tile(Bl, wb + k0, tid);
    __syncthreads();  // drains vmcnt -> tiles resident

    short8 ah[4], al[4], bh[4], bl[4];
#pragma unroll
    for (int mi = 0; mi < 4; ++mi) {
      int ro = (wr * 64 + mi * 16 + lr) * 32 + lg * 8;
      ah[mi] = *(const short8*)&Ah[ro];
      al[mi] = *(const short8*)&Al[ro];
    }
#pragma unroll
    for (int ji = 0; ji < 4; ++ji) {
      int ro = (wc * 64 + ji * 16 + lr) * 32 + lg * 8;
      bh[ji] = *(const short8*)&Bh[ro];
      bl[ji] = *(const short8*)&Bl[ro];
    }
#pragma unroll
    for (int mi = 0; mi < 4; ++mi)
#pragma unroll
      for (int ji = 0; ji < 4; ++ji) {
        acc[mi][ji] = __builtin_amdgcn_mfma_f32_16x16x32_bf16(
            ah[mi], bh[ji], acc[mi][ji], 0, 0, 0);
        acc[mi][ji] = __builtin_amdgcn_mfma_f32_16x16x32_bf16(
            ah[mi], bl[ji], acc[mi][ji], 0, 0, 0);
        acc[mi][ji] = __builtin_amdgcn_mfma_f32_16x16x32_bf16(
            al[mi], bh[ji], acc[mi][ji], 0, 0, 0);
      }
    __syncthreads();
  }

  const int which = j0 >> 9;
  const int hh = ((j0 >> 6) + wc) & 7;
  float bias_r[4];
#pragma unroll
  for (int ji = 0; ji < 4; ++ji) bias_r[ji] = bias[j0 + wc * 64 + ji * 16 + lr];

#pragma unroll
  for (int mi = 0; mi < 4; ++mi)
#pragma unroll
    for (int t = 0; t < 4; ++t) {
      int m = m0 + wr * 64 + mi * 16 + lg * 4 + t;
      int b = m >> 10, n = m & 1023;
      size_t rb = ((size_t)(b * 8 + hh) << 16) + (size_t)n * 64;
#pragma unroll
      for (int ji = 0; ji < 4; ++ji) {
        float val = acc[mi][ji][t] + bias_r[ji];
        int dd = ji * 16 + lr;
        if (which == 2) {
          vbuf[rb + dd] = val;
        } else if (which == 0) {
          qhi[rb + dd] = f2bf(val);
          qf[rb + dd] = val;
        } else {
          khi[rb + dd] = f2bf(val);
          kf[rb + dd] = val;
        }
      }
    }
}

// -------------------------------------------- float-domain packed-key top-4
__device__ __forceinline__ float packkey(float s, uint_t j) {
  return __uint_as_float((__float_as_uint(s) & 0xFFFFFC00u) | j);
}

// sort 4 keys descending (5-comparator network, depth 3)
__device__ __forceinline__ void sort4f(float& a, float& b, float& c,
                                       float& d) {
  float t;
  t = fmaxf(a, b); b = fminf(a, b); a = t;
  t = fmaxf(c, d); d = fminf(c, d); c = t;
  t = fmaxf(a, c); c = fminf(a, c); a = t;
  t = fmaxf(b, d); d = fminf(b, d); b = t;
  t = fmaxf(b, c); c = fminf(b, c); b = t;
}

// state s0>=s1>=s2>=s3; cand a>=b>=c>=d. Bitonic merge keep-top-4 + resort.
__device__ __forceinline__ void merge44f(float& s0, float& s1, float& s2,
                                         float& s3, float a, float b, float c,
                                         float d) {
  s0 = fmaxf(s0, d); s1 = fmaxf(s1, c); s2 = fmaxf(s2, b); s3 = fmaxf(s3, a);
  float t;
  t = fmaxf(s0, s2); s2 = fminf(s0, s2); s0 = t;
  t = fmaxf(s1, s3); s3 = fminf(s1, s3); s1 = t;
  t = fmaxf(s0, s1); s1 = fminf(s0, s1); s0 = t;
  t = fmaxf(s2, s3); s3 = fminf(s2, s3); s2 = t;
}

// -------------------------------------------------------- float insert4
__device__ __forceinline__ void insert4(float sc, int jv, float& s0, float& s1,
                                        float& s2, float& s3, int& i0, int& i1,
                                        int& i2, int& i3) {
  bool c = sc > s3;
  s3 = c ? sc : s3; i3 = c ? jv : i3;
  c = s3 > s2;
  { float t = c ? s2 : s3; s2 = c ? s3 : s2; s3 = t;
    int q = c ? i2 : i3; i2 = c ? i3 : i2; i3 = q; }
  c = s2 > s1;
  { float t = c ? s1 : s2; s1 = c ? s2 : s1; s2 = t;
    int q = c ? i1 : i2; i1 = c ? i2 : i1; i2 = q; }
  c = s1 > s0;
  { float t = c ? s0 : s1; s0 = c ? s1 : s0; s1 = t;
    int q = c ? i0 : i1; i0 = c ? i1 : i0; i1 = q; }
}

// ---------------------------------------------------------------- fused attn
// grid = 1024 (bh = bid&63 -> same-bh blocks share an XCD; rg = bid>>6).
// 512 thr = 8 waves: (w>>2) = 32-row half, (w&3) = 256-wide j-quarter.
// Stage A: 1-pass bf16 MFMA scores, K prefetched 2 iterations deep
//   (~150+ cycles load->use distance), float-key sort4+merge44 top-4.
// Stage B: 16 finalists/row rescored EXACTLY from fp32 q/k (pure fma).
// Stage C: V-gather weighted sum, atomicAdd.
// launch_bounds (512,6): VGPR cap 85; current pressure ~70 -> no spill
// (R7's spill was at much higher Stage-B pressure). Watch WRITE_SIZE.
__global__ __launch_bounds__(512, 6) void attn_topk_mfma(
    const ushort_t* __restrict__ khi, const ushort_t* __restrict__ qhi,
    const float* __restrict__ kf, const float* __restrict__ qf,
    const float* __restrict__ vg, float* __restrict__ out) {
  __shared__ uint_t kLp[64][17];  // packed keys (bit pattern), pad 17
  __shared__ float scL[64][17];   // exact rescored, pad 17
  __shared__ float wgt[64][5];
  __shared__ int widx[64][5];
  __shared__ float accb[8][64];

  const int bid = blockIdx.x;
  const int bh = bid & 63;
  const int rg = bid >> 6;
  const int tid = threadIdx.x;
  const int w = tid >> 6, l = tid & 63;
  const int lg = l >> 4, lr = l & 15;
  const int jq = w & 3, rowhalf = w >> 2;

  const int bhbase = bh << 16;  // bh * 1024 * 64 (fits int)
  const int rowbase = rg * 64 + rowhalf * 32;

  // Q hi fragments: 2 rowsets x 2 d-chunks (scan uses hi only)
  short8 qh[2][2];
#pragma unroll
  for (int rs = 0; rs < 2; ++rs)
#pragma unroll
    for (int c = 0; c < 2; ++c) {
      int a = bhbase + (rowbase + rs * 16 + lr) * 64 + c * 32 + lg * 8;
      qh[rs][c] = *(const short8*)(qhi + a);
    }

  float K[2][4];
#pragma unroll
  for (int rs = 0; rs < 2; ++rs)
#pragma unroll
    for (int t = 0; t < 4; ++t) K[rs][t] = NEG_INF;

  const uint_t jlane = (uint_t)(lg * 4);
  const int jt0 = jq * 16;

  // ---- Stage A: prefilter scan, K prefetched 2 iterations deep
  {
    const int kbase = bhbase + lr * 64 + lg * 8;
    short8 a0 = *(const short8*)(khi + kbase + jt0 * 1024);
    short8 a1 = *(const short8*)(khi + kbase + jt0 * 1024 + 32);
    short8 b0 = *(const short8*)(khi + kbase + (jt0 + 1) * 1024);
    short8 b1 = *(const short8*)(khi + kbase + (jt0 + 1) * 1024 + 32);
#pragma unroll
    for (int i = 0; i < 16; ++i) {
      short8 n0, n1;
      if (i < 14) {
        const int ka = kbase + (jt0 + i + 2) * 1024;
        n0 = *(const short8*)(khi + ka);
        n1 = *(const short8*)(khi + ka + 32);
      }
      const uint_t jbase = (uint_t)((jt0 + i) * 16) + jlane;
#pragma unroll
      for (int rs = 0; rs < 2; ++rs) {
        f32x4 aA = {0.f, 0.f, 0.f, 0.f};
        aA = __builtin_amdgcn_mfma_f32_16x16x32_bf16(a0, qh[rs][0], aA, 0, 0, 0);
        aA = __builtin_amdgcn_mfma_f32_16x16x32_bf16(a1, qh[rs][1], aA, 0, 0, 0);
        float ca = packkey(aA[0], jbase);
        float cb = packkey(aA[1], jbase + 1);
        float cc = packkey(aA[2], jbase + 2);
        float cd = packkey(aA[3], jbase + 3);
        sort4f(ca, cb, cc, cd);
        merge44f(K[rs][0], K[rs][1], K[rs][2], K[rs][3], ca, cb, cc, cd);
      }
      a0 = b0; a1 = b1;
      if (i < 14) { b0 = n0; b1 = n1; }
    }
  }

  // intra-wave merge of the 4 lane-groups (disjoint j subsets) per q-row
#pragma unroll
  for (int rs = 0; rs < 2; ++rs) {
#pragma unroll
    for (int mask = 16; mask <= 32; mask <<= 1) {
      float o0 = __shfl_xor(K[rs][0], mask), o1 = __shfl_xor(K[rs][1], mask);
      float o2 = __shfl_xor(K[rs][2], mask), o3 = __shfl_xor(K[rs][3], mask);
      merge44f(K[rs][0], K[rs][1], K[rs][2], K[rs][3], o0, o1, o2, o3);
    }
    if (l < 16) {
      int r = rowhalf * 32 + rs * 16 + l;
      kLp[r][jq * 4 + 0] = __float_as_uint(K[rs][0]);
      kLp[r][jq * 4 + 1] = __float_as_uint(K[rs][1]);
      kLp[r][jq * 4 + 2] = __float_as_uint(K[rs][2]);
      kLp[r][jq * 4 + 3] = __float_as_uint(K[rs][3]);
    }
  }
  __syncthreads();

  // ---- Stage B: exact rescore of 16 finalists per row (fp32 q/k, pure fma)
  // wave w owns rows w*8 .. w*8+7; lane = cand(0..15)*4 + dgroup(0..3)
  {
    const int c16 = l >> 2;
    const int dg = l & 3;
#pragma unroll
    for (int rr = 0; rr < 8; ++rr) {
      int r = w * 8 + rr;
      int j = (int)(kLp[r][c16] & 1023u);
      const f32x4* qp = (const f32x4*)(qf + bhbase + (rg * 64 + r) * 64 + dg * 16);
      const f32x4* kp = (const f32x4*)(kf + bhbase + j * 64 + dg * 16);
      float s = 0.f;
#pragma unroll
      for (int v4 = 0; v4 < 4; ++v4) {
        f32x4 qv = qp[v4];
        f32x4 kv = kp[v4];
        s = fmaf(qv[0], kv[0], s);
        s = fmaf(qv[1], kv[1], s);
        s = fmaf(qv[2], kv[2], s);
        s = fmaf(qv[3], kv[3], s);
      }
      s += __shfl_xor(s, 1);
      s += __shfl_xor(s, 2);
      if (dg == 0) scL[r][c16] = s;
    }
  }
  __syncthreads();

  // final top-4 over 16 exact scores + softmax (one thread per row)
  if (tid < 64) {
    float s0 = NEG_INF, s1 = NEG_INF, s2 = NEG_INF, s3 = NEG_INF;
    int i0 = 0, i1 = 0, i2 = 0, i3 = 0;
#pragma unroll
    for (int c = 0; c < 16; ++c) {
      float sc = scL[tid][c];
      int jv = (int)(kLp[tid][c] & 1023u);
      insert4(sc, jv, s0, s1, s2, s3, i0, i1, i2, i3);
    }
    float m = s0;
    float e0 = expf(s0 - m), e1 = expf(s1 - m);
    float e2 = expf(s2 - m), e3 = expf(s3 - m);
    float inv = 1.f / (e0 + e1 + e2 + e3);
    wgt[tid][0] = e0 * inv; wgt[tid][1] = e1 * inv;
    wgt[tid][2] = e2 * inv; wgt[tid][3] = e3 * inv;
    widx[tid][0] = i0; widx[tid][1] = i1; widx[tid][2] = i2; widx[tid][3] = i3;
  }
  __syncthreads();

  // ---- Stage C: lane = d; gather V, weight, multiply q, accumulate
  const float* vbh = vg + (size_t)bhbase;
  float acc = 0.f;
#pragma unroll
  for (int rr = 0; rr < 8; ++rr) {
    int r = w * 8 + rr;
    float w0 = wgt[r][0], w1 = wgt[r][1], w2 = wgt[r][2], w3 = wgt[r][3];
    int x0 = widx[r][0], x1 = widx[r][1], x2 = widx[r][2], x3 = widx[r][3];
    float wv = w0 * vbh[(size_t)x0 * 64 + l];
    wv = fmaf(w1, vbh[(size_t)x1 * 64 + l], wv);
    wv = fmaf(w2, vbh[(size_t)x2 * 64 + l], wv);
    wv = fmaf(w3, vbh[(size_t)x3 * 64 + l], wv);
    float qv = qf[bhbase + (rg * 64 + r) * 64 + l];
    acc = fmaf(wv, qv, acc);
  }
  accb[w][l] = acc;
  __syncthreads();
  if (w == 0) {
    float tot = accb[0][l] + accb[1][l] + accb[2][l] + accb[3][l] +
                accb[4][l] + accb[5][l] + accb[6][l] + accb[7][l];
    int b = bh >> 3, hh = bh & 7;
    atomicAdd(&out[(size_t)b * Cc + l * Hc + hh], tot);
  }
}

// ---------------------------------------------------------------- launch
extern "C" void kernel_launch(void* const* d_in, const int* in_sizes, int n_in,
                              void* d_out, int out_size, void* d_ws,
                              size_t ws_size, hipStream_t stream) {
  (void)in_sizes; (void)n_in; (void)out_size; (void)ws_size;
  const float* x = (const float*)d_in[0];
  const float* wq = (const float*)d_in[1];
  const float* bias = (const float*)d_in[2];
  float* out = (float*)d_out;

  float* vbuf = (float*)d_ws;               // QSZ f32  (16.8 MB)
  float* kf = vbuf + QSZ;                   // QSZ f32  (16.8 MB)
  float* qf = kf + QSZ;                     // QSZ f32  (16.8 MB)
  ushort_t* khi = (ushort_t*)(qf + QSZ);    // QSZ bf16 (8.4 MB)
  ushort_t* qhi = khi + QSZ;                // QSZ bf16 (8.4 MB)
  ushort_t* xth = qhi + QSZ;                // XTSZ bf16 each (8.4 MB x2)
  ushort_t* xtl = xth + XTSZ;
  ushort_t* wth = xtl + XTSZ;               // WTSZ bf16 each (1.6 MB x2)
  ushort_t* wtl = wth + WTSZ;

  zero_out_k<<<dim3((Bc * Cc + 255) / 256), 256, 0, stream>>>(out);
  conv_x<<<dim3(16, 8, 8), 256, 0, stream>>>(x, xth, xtl);
  conv_w<<<dim3(24, 8), 256, 0, stream>>>(wq, wth, wtl);
  qkv_gemm_mfma<<<dim3(64, 12), 256, 0, stream>>>(
      xth, xtl, wth, wtl, bias, vbuf, kf, qf, khi, qhi);
  attn_topk_mfma<<<dim3(1024), 512, 0, stream>>>(khi, qhi, kf, qf, vbuf, out);
}

// Round 13
// 120.907 us; speedup vs baseline: 1.2708x; 1.2708x over previous
//
#include <hip/hip_runtime.h>

#define NEG_INF (-3.402823466e+38f)

constexpr int Bc = 8, Cc = 512, Hc = 8, Dc = 64, Nc = 1024;
constexpr size_t QSZ = (size_t)Bc * Hc * Nc * Dc;  // 4,194,304 elements
constexpr size_t XTSZ = (size_t)8192 * 512;        // = QSZ
constexpr size_t WTSZ = (size_t)1536 * 512;

typedef __attribute__((ext_vector_type(8))) short short8;
typedef __attribute__((ext_vector_type(4))) float f32x4;
typedef unsigned short ushort_t;
typedef unsigned int uint_t;

// ------------------------------------------------------------ bf16 helpers
__device__ __forceinline__ ushort_t f2bf(float x) {
  uint_t u = __float_as_uint(x);
  u += 0x7FFFu + ((u >> 16) & 1u);  // round-to-nearest-even
  return (ushort_t)(u >> 16);
}
__device__ __forceinline__ float bf2f(ushort_t h) {
  return __uint_as_float(((uint_t)h) << 16);
}

// ---------------------------------------------------------------- zero output
__global__ void zero_out_k(float* __restrict__ o) {
  int i = blockIdx.x * 256 + threadIdx.x;
  if (i < Bc * Cc) o[i] = 0.f;
}

// ------------------------------------------------- transpose x -> xt (bf16)
__global__ __launch_bounds__(256) void conv_x(const float* __restrict__ x,
                                              ushort_t* __restrict__ xh) {
  __shared__ float t[64][65];
  const int b = blockIdx.z, c0 = blockIdx.y * 64, n0 = blockIdx.x * 64;
  const int tid = threadIdx.x;
  const int lc = tid & 63, lr = tid >> 6;
#pragma unroll
  for (int i = 0; i < 16; ++i) {
    int cc = lr + i * 4;
    t[cc][lc] = x[((size_t)(b * 512 + c0 + cc)) * 1024 + n0 + lc];
  }
  __syncthreads();
#pragma unroll
  for (int i = 0; i < 16; ++i) {
    int nn = lr + i * 4;
    xh[((size_t)(b * 1024 + n0 + nn)) * 512 + c0 + lc] = f2bf(t[lc][nn]);
  }
}

// ---------------------------------- transpose+split W -> wt hi/lo (bf16 x2)
// W is the small operand (1536x512); splitting it keeps GEMM values at
// ~0.002 abs error (only x's 1-pass rounding remains).
__global__ __launch_bounds__(256) void conv_w(const float* __restrict__ wq,
                                              ushort_t* __restrict__ wh,
                                              ushort_t* __restrict__ wl) {
  __shared__ float t[64][65];
  const int c0 = blockIdx.y * 64, j0 = blockIdx.x * 64;
  const int tid = threadIdx.x;
  const int lj = tid & 63, lr = tid >> 6;
#pragma unroll
  for (int i = 0; i < 16; ++i) {
    int cc = lr + i * 4;
    t[cc][lj] = wq[(size_t)(c0 + cc) * 1536 + j0 + lj];
  }
  __syncthreads();
#pragma unroll
  for (int i = 0; i < 16; ++i) {
    int jj = lr + i * 4;
    float v = t[lj][jj];  // = W[c0+lj][j0+jj]
    ushort_t h = f2bf(v);
    size_t o = (size_t)(j0 + jj) * 512 + c0 + lj;
    wh[o] = h;
    wl[o] = f2bf(v - bf2f(h));
  }
}

// ------------------------------------------------------ async stage helper
__device__ __forceinline__ void stage_tile(ushort_t* lds, const ushort_t* g,
                                           int tid) {
  typedef const __attribute__((address_space(1))) unsigned int GU;
  typedef __attribute__((address_space(3))) unsigned int LU;
  {
    int l = tid, r = l >> 2, c = (l & 3) * 8;
    __builtin_amdgcn_global_load_lds((GU*)(g + (size_t)r * 512 + c),
                                     (LU*)(lds + (size_t)l * 8), 16, 0, 0);
  }
  {
    int l = tid + 256, r = l >> 2, c = (l & 3) * 8;
    __builtin_amdgcn_global_load_lds((GU*)(g + (size_t)r * 512 + c),
                                     (LU*)(lds + (size_t)l * 8), 16, 0, 0);
  }
}

// ---------------------------------------------------------------- QKV GEMM
// 2-pass: C = x_bf * (W_hi + W_lo). Value error ~0.002 (x rounding only) --
// the fp32 rescore path (qf/kf) needs this; the bf16 scan path tolerates
// more. 32 MFMA + 3 staged tiles per k-step.
__global__ __launch_bounds__(256) void qkv_gemm_mfma(
    const ushort_t* __restrict__ xth, const ushort_t* __restrict__ wth,
    const ushort_t* __restrict__ wtl, const float* __restrict__ bias,
    float* __restrict__ vbuf, float* __restrict__ kf, float* __restrict__ qf,
    ushort_t* __restrict__ khi, ushort_t* __restrict__ qhi) {
  __shared__ __align__(16) ushort_t Ah[128 * 32];
  __shared__ __align__(16) ushort_t Bh[128 * 32];
  __shared__ __align__(16) ushort_t Bl[128 * 32];

  const int m0 = blockIdx.x * 128, j0 = blockIdx.y * 128;
  const int tid = threadIdx.x;
  const int w = tid >> 6, l = tid & 63;
  const int lr = l & 15, lg = l >> 4;
  const int wr = w >> 1, wc = w & 1;

  f32x4 acc[4][4];
#pragma unroll
  for (int i = 0; i < 4; ++i)
#pragma unroll
    for (int j = 0; j < 4; ++j) acc[i][j] = (f32x4){0.f, 0.f, 0.f, 0.f};

  const ushort_t* xa = xth + (size_t)m0 * 512;
  const ushort_t* wa = wth + (size_t)j0 * 512;
  const ushort_t* wb = wtl + (size_t)j0 * 512;

  for (int s = 0; s < 16; ++s) {
    const int k0 = s * 32;
    stage_tile(Ah, xa + k0, tid);
    stage_tile(Bh, wa + k0, tid);
    stage_tile(Bl, wb + k0, tid);
    __syncthreads();  // drains vmcnt -> tiles resident

    short8 ah[4], bh[4], bl[4];
#pragma unroll
    for (int mi = 0; mi < 4; ++mi)
      ah[mi] = *(const short8*)&Ah[(wr * 64 + mi * 16 + lr) * 32 + lg * 8];
#pragma unroll
    for (int ji = 0; ji < 4; ++ji) {
      int ro = (wc * 64 + ji * 16 + lr) * 32 + lg * 8;
      bh[ji] = *(const short8*)&Bh[ro];
      bl[ji] = *(const short8*)&Bl[ro];
    }
#pragma unroll
    for (int mi = 0; mi < 4; ++mi)
#pragma unroll
      for (int ji = 0; ji < 4; ++ji) {
        acc[mi][ji] = __builtin_amdgcn_mfma_f32_16x16x32_bf16(
            ah[mi], bh[ji], acc[mi][ji], 0, 0, 0);
        acc[mi][ji] = __builtin_amdgcn_mfma_f32_16x16x32_bf16(
            ah[mi], bl[ji], acc[mi][ji], 0, 0, 0);
      }
    __syncthreads();
  }

  const int which = j0 >> 9;
  const int hh = ((j0 >> 6) + wc) & 7;
  float bias_r[4];
#pragma unroll
  for (int ji = 0; ji < 4; ++ji) bias_r[ji] = bias[j0 + wc * 64 + ji * 16 + lr];

#pragma unroll
  for (int mi = 0; mi < 4; ++mi)
#pragma unroll
    for (int t = 0; t < 4; ++t) {
      int m = m0 + wr * 64 + mi * 16 + lg * 4 + t;
      int b = m >> 10, n = m & 1023;
      size_t rb = ((size_t)(b * 8 + hh) << 16) + (size_t)n * 64;
#pragma unroll
      for (int ji = 0; ji < 4; ++ji) {
        float val = acc[mi][ji][t] + bias_r[ji];
        int dd = ji * 16 + lr;
        if (which == 2) {
          vbuf[rb + dd] = val;
        } else if (which == 0) {
          qhi[rb + dd] = f2bf(val);
          qf[rb + dd] = val;
        } else {
          khi[rb + dd] = f2bf(val);
          kf[rb + dd] = val;
        }
      }
    }
}

// -------------------------------------------- float-domain packed-key top-4
__device__ __forceinline__ float packkey(float s, uint_t j) {
  return __uint_as_float((__float_as_uint(s) & 0xFFFFFC00u) | j);
}

// sort 4 keys descending (5-comparator network, depth 3)
__device__ __forceinline__ void sort4f(float& a, float& b, float& c,
                                       float& d) {
  float t;
  t = fmaxf(a, b); b = fminf(a, b); a = t;
  t = fmaxf(c, d); d = fminf(c, d); c = t;
  t = fmaxf(a, c); c = fminf(a, c); a = t;
  t = fmaxf(b, d); d = fminf(b, d); b = t;
  t = fmaxf(b, c); c = fminf(b, c); b = t;
}

// state s0>=s1>=s2>=s3; cand a>=b>=c>=d. Bitonic keep-top-4 + resort.
__device__ __forceinline__ void merge44f(float& s0, float& s1, float& s2,
                                         float& s3, float a, float b, float c,
                                         float d) {
  s0 = fmaxf(s0, d); s1 = fmaxf(s1, c); s2 = fmaxf(s2, b); s3 = fmaxf(s3, a);
  float t;
  t = fmaxf(s0, s2); s2 = fminf(s0, s2); s0 = t;
  t = fmaxf(s1, s3); s3 = fminf(s1, s3); s1 = t;
  t = fmaxf(s0, s1); s1 = fminf(s0, s1); s0 = t;
  t = fmaxf(s2, s3); s3 = fminf(s2, s3); s2 = t;
}

// -------------------------------------------------------- float insert4
__device__ __forceinline__ void insert4(float sc, int jv, float& s0, float& s1,
                                        float& s2, float& s3, int& i0, int& i1,
                                        int& i2, int& i3) {
  bool c = sc > s3;
  s3 = c ? sc : s3; i3 = c ? jv : i3;
  c = s3 > s2;
  { float t = c ? s2 : s3; s2 = c ? s3 : s2; s3 = t;
    int q = c ? i2 : i3; i2 = c ? i3 : i2; i3 = q; }
  c = s2 > s1;
  { float t = c ? s1 : s2; s1 = c ? s2 : s1; s2 = t;
    int q = c ? i1 : i2; i1 = c ? i2 : i1; i2 = q; }
  c = s1 > s0;
  { float t = c ? s0 : s1; s0 = c ? s1 : s0; s1 = t;
    int q = c ? i0 : i1; i0 = c ? i1 : i0; i1 = q; }
}

// ---------------------------------------------------------------- fused attn
// grid = 1024 (bh = bid&63 -> same-bh blocks share an XCD; rg = bid>>6).
// 512 thr = 8 waves: (w>>2) = 32-row half, (w&3) = 256-wide j-quarter.
// Stage A: bf16 MFMA scores, K prefetched 2 deep, float-key sort top-4.
// Stage B: 16 finalists/row rescored from fp32 qf/kf (pure fma).
// Stage C: V-gather weighted sum, atomicAdd.
// launch_bounds MUST stay (512,4): (512,6) spills (R7, R11: ~95MB WRITE).
__global__ __launch_bounds__(512, 4) void attn_topk_mfma(
    const ushort_t* __restrict__ khi, const ushort_t* __restrict__ qhi,
    const float* __restrict__ kf, const float* __restrict__ qf,
    const float* __restrict__ vg, float* __restrict__ out) {
  __shared__ uint_t kLp[64][17];  // packed keys (bit pattern), pad 17
  __shared__ float scL[64][17];   // exact rescored, pad 17
  __shared__ float wgt[64][5];
  __shared__ int widx[64][5];
  __shared__ float accb[8][64];

  const int bid = blockIdx.x;
  const int bh = bid & 63;
  const int rg = bid >> 6;
  const int tid = threadIdx.x;
  const int w = tid >> 6, l = tid & 63;
  const int lg = l >> 4, lr = l & 15;
  const int jq = w & 3, rowhalf = w >> 2;

  const int bhbase = bh << 16;  // bh * 1024 * 64 (fits int)
  const int rowbase = rg * 64 + rowhalf * 32;

  // Q fragments: 2 rowsets x 2 d-chunks
  short8 qh[2][2];
#pragma unroll
  for (int rs = 0; rs < 2; ++rs)
#pragma unroll
    for (int c = 0; c < 2; ++c) {
      int a = bhbase + (rowbase + rs * 16 + lr) * 64 + c * 32 + lg * 8;
      qh[rs][c] = *(const short8*)(qhi + a);
    }

  float K[2][4];
#pragma unroll
  for (int rs = 0; rs < 2; ++rs)
#pragma unroll
    for (int t = 0; t < 4; ++t) K[rs][t] = NEG_INF;

  const uint_t jlane = (uint_t)(lg * 4);
  const int jt0 = jq * 16;

  // ---- Stage A: prefilter scan, K prefetched 2 iterations deep
  {
    const int kbase = bhbase + lr * 64 + lg * 8;
    short8 a0 = *(const short8*)(khi + kbase + jt0 * 1024);
    short8 a1 = *(const short8*)(khi + kbase + jt0 * 1024 + 32);
    short8 b0 = *(const short8*)(khi + kbase + (jt0 + 1) * 1024);
    short8 b1 = *(const short8*)(khi + kbase + (jt0 + 1) * 1024 + 32);
#pragma unroll
    for (int i = 0; i < 16; ++i) {
      short8 n0, n1;
      if (i < 14) {
        const int ka = kbase + (jt0 + i + 2) * 1024;
        n0 = *(const short8*)(khi + ka);
        n1 = *(const short8*)(khi + ka + 32);
      }
      const uint_t jbase = (uint_t)((jt0 + i) * 16) + jlane;
#pragma unroll
      for (int rs = 0; rs < 2; ++rs) {
        f32x4 aA = {0.f, 0.f, 0.f, 0.f};
        aA = __builtin_amdgcn_mfma_f32_16x16x32_bf16(a0, qh[rs][0], aA, 0, 0, 0);
        aA = __builtin_amdgcn_mfma_f32_16x16x32_bf16(a1, qh[rs][1], aA, 0, 0, 0);
        float ca = packkey(aA[0], jbase);
        float cb = packkey(aA[1], jbase + 1);
        float cc = packkey(aA[2], jbase + 2);
        float cd = packkey(aA[3], jbase + 3);
        sort4f(ca, cb, cc, cd);
        merge44f(K[rs][0], K[rs][1], K[rs][2], K[rs][3], ca, cb, cc, cd);
      }
      a0 = b0; a1 = b1;
      if (i < 14) { b0 = n0; b1 = n1; }
    }
  }

  // intra-wave merge of the 4 lane-groups (disjoint j subsets) per q-row
#pragma unroll
  for (int rs = 0; rs < 2; ++rs) {
#pragma unroll
    for (int mask = 16; mask <= 32; mask <<= 1) {
      float o0 = __shfl_xor(K[rs][0], mask), o1 = __shfl_xor(K[rs][1], mask);
      float o2 = __shfl_xor(K[rs][2], mask), o3 = __shfl_xor(K[rs][3], mask);
      merge44f(K[rs][0], K[rs][1], K[rs][2], K[rs][3], o0, o1, o2, o3);
    }
    if (l < 16) {
      int r = rowhalf * 32 + rs * 16 + l;
      kLp[r][jq * 4 + 0] = __float_as_uint(K[rs][0]);
      kLp[r][jq * 4 + 1] = __float_as_uint(K[rs][1]);
      kLp[r][jq * 4 + 2] = __float_as_uint(K[rs][2]);
      kLp[r][jq * 4 + 3] = __float_as_uint(K[rs][3]);
    }
  }
  __syncthreads();

  // ---- Stage B: rescore 16 finalists/row from fp32 qf/kf (pure fma)
  // wave w owns rows w*8 .. w*8+7; lane = cand(0..15)*4 + dgroup(0..3)
  {
    const int c16 = l >> 2;
    const int dg = l & 3;
#pragma unroll
    for (int rr = 0; rr < 8; ++rr) {
      int r = w * 8 + rr;
      int j = (int)(kLp[r][c16] & 1023u);
      const f32x4* qp =
          (const f32x4*)(qf + bhbase + (rg * 64 + r) * 64 + dg * 16);
      const f32x4* kp = (const f32x4*)(kf + bhbase + j * 64 + dg * 16);
      float s = 0.f;
#pragma unroll
      for (int v4 = 0; v4 < 4; ++v4) {
        f32x4 qv = qp[v4];
        f32x4 kv = kp[v4];
        s = fmaf(qv[0], kv[0], s);
        s = fmaf(qv[1], kv[1], s);
        s = fmaf(qv[2], kv[2], s);
        s = fmaf(qv[3], kv[3], s);
      }
      s += __shfl_xor(s, 1);
      s += __shfl_xor(s, 2);
      if (dg == 0) scL[r][c16] = s;
    }
  }
  __syncthreads();

  // final top-4 over 16 exact scores + softmax (one thread per row)
  if (tid < 64) {
    float s0 = NEG_INF, s1 = NEG_INF, s2 = NEG_INF, s3 = NEG_INF;
    int i0 = 0, i1 = 0, i2 = 0, i3 = 0;
#pragma unroll
    for (int c = 0; c < 16; ++c) {
      float sc = scL[tid][c];
      int jv = (int)(kLp[tid][c] & 1023u);
      insert4(sc, jv, s0, s1, s2, s3, i0, i1, i2, i3);
    }
    float m = s0;
    float e0 = expf(s0 - m), e1 = expf(s1 - m);
    float e2 = expf(s2 - m), e3 = expf(s3 - m);
    float inv = 1.f / (e0 + e1 + e2 + e3);
    wgt[tid][0] = e0 * inv; wgt[tid][1] = e1 * inv;
    wgt[tid][2] = e2 * inv; wgt[tid][3] = e3 * inv;
    widx[tid][0] = i0; widx[tid][1] = i1; widx[tid][2] = i2; widx[tid][3] = i3;
  }
  __syncthreads();

  // ---- Stage C: lane = d; gather V, weight, multiply q, accumulate
  const float* vbh = vg + (size_t)bhbase;
  float acc = 0.f;
#pragma unroll
  for (int rr = 0; rr < 8; ++rr) {
    int r = w * 8 + rr;
    float w0 = wgt[r][0], w1 = wgt[r][1], w2 = wgt[r][2], w3 = wgt[r][3];
    int x0 = widx[r][0], x1 = widx[r][1], x2 = widx[r][2], x3 = widx[r][3];
    float wv = w0 * vbh[(size_t)x0 * 64 + l];
    wv = fmaf(w1, vbh[(size_t)x1 * 64 + l], wv);
    wv = fmaf(w2, vbh[(size_t)x2 * 64 + l], wv);
    wv = fmaf(w3, vbh[(size_t)x3 * 64 + l], wv);
    float qv = qf[bhbase + (rg * 64 + r) * 64 + l];
    acc = fmaf(wv, qv, acc);
  }
  accb[w][l] = acc;
  __syncthreads();
  if (w == 0) {
    float tot = accb[0][l] + accb[1][l] + accb[2][l] + accb[3][l] +
                accb[4][l] + accb[5][l] + accb[6][l] + accb[7][l];
    int b = bh >> 3, hh = bh & 7;
    atomicAdd(&out[(size_t)b * Cc + l * Hc + hh], tot);
  }
}

// ---------------------------------------------------------------- launch
extern "C" void kernel_launch(void* const* d_in, const int* in_sizes, int n_in,
                              void* d_out, int out_size, void* d_ws,
                              size_t ws_size, hipStream_t stream) {
  (void)in_sizes; (void)n_in; (void)out_size; (void)ws_size;
  const float* x = (const float*)d_in[0];
  const float* wq = (const float*)d_in[1];
  const float* bias = (const float*)d_in[2];
  float* out = (float*)d_out;

  float* vbuf = (float*)d_ws;               // QSZ f32  (16.8 MB)
  float* kf = vbuf + QSZ;                   // QSZ f32  (16.8 MB)
  float* qf = kf + QSZ;                     // QSZ f32  (16.8 MB)
  ushort_t* khi = (ushort_t*)(qf + QSZ);    // QSZ bf16 (8.4 MB)
  ushort_t* qhi = khi + QSZ;                // QSZ bf16 (8.4 MB)
  ushort_t* xth = qhi + QSZ;                // XTSZ bf16 (8.4 MB)
  ushort_t* wth = xth + XTSZ;               // WTSZ bf16 (1.6 MB)
  ushort_t* wtl = wth + WTSZ;               // WTSZ bf16 (1.6 MB)

  zero_out_k<<<dim3((Bc * Cc + 255) / 256), 256, 0, stream>>>(out);
  conv_x<<<dim3(16, 8, 8), 256, 0, stream>>>(x, xth);
  conv_w<<<dim3(24, 8), 256, 0, stream>>>(wq, wth, wtl);
  qkv_gemm_mfma<<<dim3(64, 12), 256, 0, stream>>>(xth, wth, wtl, bias, vbuf,
                                                  kf, qf, khi, qhi);
  attn_topk_mfma<<<dim3(1024), 512, 0, stream>>>(khi, qhi, kf, qf, vbuf, out);
}

// Round 14
// 92.529 us; speedup vs baseline: 1.6605x; 1.3067x over previous
//
#include <hip/hip_runtime.h>

#define NEG_INF (-3.402823466e+38f)

constexpr int Bc = 8, Cc = 512, Hc = 8, Dc = 64, Nc = 1024;
constexpr size_t QSZ = (size_t)Bc * Hc * Nc * Dc;  // 4,194,304 elements
constexpr size_t XTSZ = (size_t)8192 * 512;        // = QSZ
constexpr size_t WTSZ = (size_t)1536 * 512;

typedef __attribute__((ext_vector_type(8))) short short8;
typedef __attribute__((ext_vector_type(4))) float f32x4;
typedef unsigned short ushort_t;
typedef unsigned int uint_t;

// ------------------------------------------------------------ bf16 helpers
__device__ __forceinline__ ushort_t f2bf(float x) {
  uint_t u = __float_as_uint(x);
  u += 0x7FFFu + ((u >> 16) & 1u);  // round-to-nearest-even
  return (ushort_t)(u >> 16);
}
__device__ __forceinline__ float bf2f(ushort_t h) {
  return __uint_as_float(((uint_t)h) << 16);
}

// ------------------------------------- transpose x -> xt (bf16) + zero out
__global__ __launch_bounds__(256) void conv_x(const float* __restrict__ x,
                                              ushort_t* __restrict__ xh,
                                              float* __restrict__ out) {
  __shared__ float t[64][65];
  const int b = blockIdx.z, c0 = blockIdx.y * 64, n0 = blockIdx.x * 64;
  const int tid = threadIdx.x;
  const int lc = tid & 63, lr = tid >> 6;
  // fold output zeroing into the first 16 blocks (out is atomicAdd target)
  int fb = (blockIdx.z * 8 + blockIdx.y) * 16 + blockIdx.x;
  if (fb < 16) out[fb * 256 + tid] = 0.f;
#pragma unroll
  for (int i = 0; i < 16; ++i) {
    int cc = lr + i * 4;
    t[cc][lc] = x[((size_t)(b * 512 + c0 + cc)) * 1024 + n0 + lc];
  }
  __syncthreads();
#pragma unroll
  for (int i = 0; i < 16; ++i) {
    int nn = lr + i * 4;
    xh[((size_t)(b * 1024 + n0 + nn)) * 512 + c0 + lc] = f2bf(t[lc][nn]);
  }
}

// ---------------------------------- transpose+split W -> wt hi/lo (bf16 x2)
__global__ __launch_bounds__(256) void conv_w(const float* __restrict__ wq,
                                              ushort_t* __restrict__ wh,
                                              ushort_t* __restrict__ wl) {
  __shared__ float t[64][65];
  const int c0 = blockIdx.y * 64, j0 = blockIdx.x * 64;
  const int tid = threadIdx.x;
  const int lj = tid & 63, lr = tid >> 6;
#pragma unroll
  for (int i = 0; i < 16; ++i) {
    int cc = lr + i * 4;
    t[cc][lj] = wq[(size_t)(c0 + cc) * 1536 + j0 + lj];
  }
  __syncthreads();
#pragma unroll
  for (int i = 0; i < 16; ++i) {
    int jj = lr + i * 4;
    float v = t[lj][jj];  // = W[c0+lj][j0+jj]
    ushort_t h = f2bf(v);
    size_t o = (size_t)(j0 + jj) * 512 + c0 + lj;
    wh[o] = h;
    wl[o] = f2bf(v - bf2f(h));
  }
}

// ------------------------------------------------------ async stage helper
__device__ __forceinline__ void stage_tile(ushort_t* lds, const ushort_t* g,
                                           int tid) {
  typedef const __attribute__((address_space(1))) unsigned int GU;
  typedef __attribute__((address_space(3))) unsigned int LU;
  {
    int l = tid, r = l >> 2, c = (l & 3) * 8;
    __builtin_amdgcn_global_load_lds((GU*)(g + (size_t)r * 512 + c),
                                     (LU*)(lds + (size_t)l * 8), 16, 0, 0);
  }
  {
    int l = tid + 256, r = l >> 2, c = (l & 3) * 8;
    __builtin_amdgcn_global_load_lds((GU*)(g + (size_t)r * 512 + c),
                                     (LU*)(lds + (size_t)l * 8), 16, 0, 0);
  }
}

// ---------------------------------------------------------------- QKV GEMM
// 2-pass: C = x_bf * (W_hi + W_lo). Value error ~0.002 (x rounding only).
__global__ __launch_bounds__(256) void qkv_gemm_mfma(
    const ushort_t* __restrict__ xth, const ushort_t* __restrict__ wth,
    const ushort_t* __restrict__ wtl, const float* __restrict__ bias,
    float* __restrict__ vbuf, float* __restrict__ kf, float* __restrict__ qf,
    ushort_t* __restrict__ khi, ushort_t* __restrict__ qhi) {
  __shared__ __align__(16) ushort_t Ah[128 * 32];
  __shared__ __align__(16) ushort_t Bh[128 * 32];
  __shared__ __align__(16) ushort_t Bl[128 * 32];

  const int m0 = blockIdx.x * 128, j0 = blockIdx.y * 128;
  const int tid = threadIdx.x;
  const int w = tid >> 6, l = tid & 63;
  const int lr = l & 15, lg = l >> 4;
  const int wr = w >> 1, wc = w & 1;

  f32x4 acc[4][4];
#pragma unroll
  for (int i = 0; i < 4; ++i)
#pragma unroll
    for (int j = 0; j < 4; ++j) acc[i][j] = (f32x4){0.f, 0.f, 0.f, 0.f};

  const ushort_t* xa = xth + (size_t)m0 * 512;
  const ushort_t* wa = wth + (size_t)j0 * 512;
  const ushort_t* wb = wtl + (size_t)j0 * 512;

  for (int s = 0; s < 16; ++s) {
    const int k0 = s * 32;
    stage_tile(Ah, xa + k0, tid);
    stage_tile(Bh, wa + k0, tid);
    stage_tile(Bl, wb + k0, tid);
    __syncthreads();  // drains vmcnt -> tiles resident

    short8 ah[4], bh[4], bl[4];
#pragma unroll
    for (int mi = 0; mi < 4; ++mi)
      ah[mi] = *(const short8*)&Ah[(wr * 64 + mi * 16 + lr) * 32 + lg * 8];
#pragma unroll
    for (int ji = 0; ji < 4; ++ji) {
      int ro = (wc * 64 + ji * 16 + lr) * 32 + lg * 8;
      bh[ji] = *(const short8*)&Bh[ro];
      bl[ji] = *(const short8*)&Bl[ro];
    }
#pragma unroll
    for (int mi = 0; mi < 4; ++mi)
#pragma unroll
      for (int ji = 0; ji < 4; ++ji) {
        acc[mi][ji] = __builtin_amdgcn_mfma_f32_16x16x32_bf16(
            ah[mi], bh[ji], acc[mi][ji], 0, 0, 0);
        acc[mi][ji] = __builtin_amdgcn_mfma_f32_16x16x32_bf16(
            ah[mi], bl[ji], acc[mi][ji], 0, 0, 0);
      }
    __syncthreads();
  }

  const int which = j0 >> 9;
  const int hh = ((j0 >> 6) + wc) & 7;
  float bias_r[4];
#pragma unroll
  for (int ji = 0; ji < 4; ++ji) bias_r[ji] = bias[j0 + wc * 64 + ji * 16 + lr];

#pragma unroll
  for (int mi = 0; mi < 4; ++mi)
#pragma unroll
    for (int t = 0; t < 4; ++t) {
      int m = m0 + wr * 64 + mi * 16 + lg * 4 + t;
      int b = m >> 10, n = m & 1023;
      size_t rb = ((size_t)(b * 8 + hh) << 16) + (size_t)n * 64;
#pragma unroll
      for (int ji = 0; ji < 4; ++ji) {
        float val = acc[mi][ji][t] + bias_r[ji];
        int dd = ji * 16 + lr;
        if (which == 2) {
          vbuf[rb + dd] = val;
        } else if (which == 0) {
          qhi[rb + dd] = f2bf(val);
          qf[rb + dd] = val;
        } else {
          khi[rb + dd] = f2bf(val);
          kf[rb + dd] = val;
        }
      }
    }
}

// -------------------------------------------- float-domain packed-key top-4
__device__ __forceinline__ float packkey(float s, uint_t j) {
  return __uint_as_float((__float_as_uint(s) & 0xFFFFFC00u) | j);
}

// sort 4 keys descending (5-comparator network, depth 3)
__device__ __forceinline__ void sort4f(float& a, float& b, float& c,
                                       float& d) {
  float t;
  t = fmaxf(a, b); b = fminf(a, b); a = t;
  t = fmaxf(c, d); d = fminf(c, d); c = t;
  t = fmaxf(a, c); c = fminf(a, c); a = t;
  t = fmaxf(b, d); d = fminf(b, d); b = t;
  t = fmaxf(b, c); c = fminf(b, c); b = t;
}

// state s0>=s1>=s2>=s3; cand a>=b>=c>=d. Bitonic keep-top-4 + resort.
__device__ __forceinline__ void merge44f(float& s0, float& s1, float& s2,
                                         float& s3, float a, float b, float c,
                                         float d) {
  s0 = fmaxf(s0, d); s1 = fmaxf(s1, c); s2 = fmaxf(s2, b); s3 = fmaxf(s3, a);
  float t;
  t = fmaxf(s0, s2); s2 = fminf(s0, s2); s0 = t;
  t = fmaxf(s1, s3); s3 = fminf(s1, s3); s1 = t;
  t = fmaxf(s0, s1); s1 = fminf(s0, s1); s0 = t;
  t = fmaxf(s2, s3); s3 = fminf(s2, s3); s2 = t;
}

// -------------------------------------------------------- float insert4
__device__ __forceinline__ void insert4(float sc, int jv, float& s0, float& s1,
                                        float& s2, float& s3, int& i0, int& i1,
                                        int& i2, int& i3) {
  bool c = sc > s3;
  s3 = c ? sc : s3; i3 = c ? jv : i3;
  c = s3 > s2;
  { float t = c ? s2 : s3; s2 = c ? s3 : s2; s3 = t;
    int q = c ? i2 : i3; i2 = c ? i3 : i2; i3 = q; }
  c = s2 > s1;
  { float t = c ? s1 : s2; s1 = c ? s2 : s1; s2 = t;
    int q = c ? i1 : i2; i1 = c ? i2 : i1; i2 = q; }
  c = s1 > s0;
  { float t = c ? s0 : s1; s0 = c ? s1 : s0; s1 = t;
    int q = c ? i0 : i1; i0 = c ? i1 : i0; i1 = q; }
}

// --------------------------------------- stage one 256j x 64d K chunk (32KB)
// LDS dest is linear (wave-uniform base + lane*16); the XOR swizzle is
// applied to the GLOBAL source address (m173 pattern), so readers use
// kt[row*64 + ((colgrp ^ (row&7)) << 3)].
__device__ __forceinline__ void stage_k_chunk(ushort_t* kt,
                                              const ushort_t* gk, int chunk,
                                              int tid) {
  typedef const __attribute__((address_space(1))) unsigned int GU;
  typedef __attribute__((address_space(3))) unsigned int LU;
#pragma unroll
  for (int ri = 0; ri < 4; ++ri) {
    int p = ri * 512 + tid;      // 0..2047
    int row = p >> 3;            // 0..255
    int colu = (p & 7) << 3;     // ushort col: 0,8,..,56
    int srcu = (chunk * 256 + row) * 64 + (colu ^ ((row & 7) << 3));
    __builtin_amdgcn_global_load_lds((GU*)(gk + srcu),
                                     (LU*)(kt + (size_t)p * 8), 16, 0, 0);
  }
}

// ---------------------------------------------------------------- fused attn
// grid = 512: bh = bid&63 (same-bh blocks share an XCD), rg = bid>>6.
// Block = 128 rows, 8 waves, each wave owns ONE 16-row rowset and scans ALL
// 1024 j from LDS-staged K (4 chunks of 256j, double-buffered, staged by
// all 512 threads via global_load_lds -> deep MLP; this was the R13
// bottleneck: ~4 outstanding loads/wave = 790 GB/s).
// Per-row finalists: 2 parity-split top-4 key states (8 finalists), exact
// fp32 rescore + softmax. Everything after the scan is wave-local (no
// barriers). launch_bounds MUST stay (512,4): (512,6) spills (R7/R11).
__global__ __launch_bounds__(512, 4) void attn_topk_mfma(
    const ushort_t* __restrict__ khi, const ushort_t* __restrict__ qhi,
    const float* __restrict__ kf, const float* __restrict__ qf,
    const float* __restrict__ vg, float* __restrict__ out) {
  __shared__ __align__(16) ushort_t KT[2][256 * 64];  // 2 x 32 KB
  __shared__ uint_t kLp[128][8];
  __shared__ float scS[128][8];
  __shared__ float wgt[128][4];
  __shared__ int widx[128][4];

  const int bid = blockIdx.x;
  const int bh = bid & 63;
  const int rg = bid >> 6;  // 0..7
  const int tid = threadIdx.x;
  const int w = tid >> 6, l = tid & 63;
  const int lg = l >> 4, lr = l & 15;

  const int bhbase = bh << 16;           // bh * 1024 * 64
  const int rowbase = rg * 128 + w * 16; // wave's first q-row (global in bh)
  const ushort_t* gk = khi + bhbase;

  // Q fragments: 1 rowset x 2 d-chunks
  short8 qh[2];
#pragma unroll
  for (int c2 = 0; c2 < 2; ++c2)
    qh[c2] = *(const short8*)(qhi + bhbase + (rowbase + lr) * 64 + c2 * 32 +
                              lg * 8);

  float Ka[4], Kb[4];
#pragma unroll
  for (int t = 0; t < 4; ++t) { Ka[t] = NEG_INF; Kb[t] = NEG_INF; }

  // prologue: stage chunk 0
  stage_k_chunk(KT[0], gk, 0, tid);
  __syncthreads();

  for (int c = 0; c < 4; ++c) {
    if (c < 3) stage_k_chunk(KT[(c + 1) & 1], gk, c + 1, tid);
    const ushort_t* kt = KT[c & 1];
    const uint_t jb0 = (uint_t)(c * 256) + (uint_t)(lg * 4);
    const int sw = lr & 7;
#pragma unroll
    for (int jtl = 0; jtl < 16; ++jtl) {
      const int rbase = (jtl * 16 + lr) * 64;
      short8 k0 = *(const short8*)&kt[rbase + ((lg ^ sw) << 3)];
      short8 k1 = *(const short8*)&kt[rbase + (((lg + 4) ^ sw) << 3)];
      f32x4 aA = {0.f, 0.f, 0.f, 0.f};
      aA = __builtin_amdgcn_mfma_f32_16x16x32_bf16(k0, qh[0], aA, 0, 0, 0);
      aA = __builtin_amdgcn_mfma_f32_16x16x32_bf16(k1, qh[1], aA, 0, 0, 0);
      const uint_t jbase = jb0 + (uint_t)(jtl * 16);
      float ca = packkey(aA[0], jbase);
      float cb = packkey(aA[1], jbase + 1);
      float cc = packkey(aA[2], jbase + 2);
      float cd = packkey(aA[3], jbase + 3);
      sort4f(ca, cb, cc, cd);
      if ((jtl & 1) == 0)
        merge44f(Ka[0], Ka[1], Ka[2], Ka[3], ca, cb, cc, cd);
      else
        merge44f(Kb[0], Kb[1], Kb[2], Kb[3], ca, cb, cc, cd);
    }
    __syncthreads();  // staged loads drained; buffer safe to reuse
  }

  // intra-wave merge of the 4 lane-groups (disjoint j subsets) per q-row
#pragma unroll
  for (int mask = 16; mask <= 32; mask <<= 1) {
    float a0 = __shfl_xor(Ka[0], mask), a1 = __shfl_xor(Ka[1], mask);
    float a2 = __shfl_xor(Ka[2], mask), a3 = __shfl_xor(Ka[3], mask);
    merge44f(Ka[0], Ka[1], Ka[2], Ka[3], a0, a1, a2, a3);
    float b0 = __shfl_xor(Kb[0], mask), b1 = __shfl_xor(Kb[1], mask);
    float b2 = __shfl_xor(Kb[2], mask), b3 = __shfl_xor(Kb[3], mask);
    merge44f(Kb[0], Kb[1], Kb[2], Kb[3], b0, b1, b2, b3);
  }
  if (l < 16) {
    int r = w * 16 + l;
#pragma unroll
    for (int t = 0; t < 4; ++t) {
      kLp[r][t] = __float_as_uint(Ka[t]);
      kLp[r][4 + t] = __float_as_uint(Kb[t]);
    }
  }
  // wave-local from here on: no __syncthreads needed (compiler orders LDS)

  // ---- Stage B: rescore 8 finalists/row from fp32 qf/kf
  // lane = cand(0..7)*8 + dg(0..7); wave rescores its own 16 rows
  {
    const int cand = l >> 3, dg = l & 7;
#pragma unroll 4
    for (int rr = 0; rr < 16; ++rr) {
      int r = w * 16 + rr;
      int j = (int)(kLp[r][cand] & 1023u);
      int qa = bhbase + (rg * 128 + r) * 64 + dg * 8;
      int ka = bhbase + j * 64 + dg * 8;
      f32x4 q0 = *(const f32x4*)(qf + qa);
      f32x4 q1 = *(const f32x4*)(qf + qa + 4);
      f32x4 k0 = *(const f32x4*)(kf + ka);
      f32x4 k1 = *(const f32x4*)(kf + ka + 4);
      float s = q0[0] * k0[0];
      s = fmaf(q0[1], k0[1], s);
      s = fmaf(q0[2], k0[2], s);
      s = fmaf(q0[3], k0[3], s);
      s = fmaf(q1[0], k1[0], s);
      s = fmaf(q1[1], k1[1], s);
      s = fmaf(q1[2], k1[2], s);
      s = fmaf(q1[3], k1[3], s);
      s += __shfl_xor(s, 1);
      s += __shfl_xor(s, 2);
      s += __shfl_xor(s, 4);
      if (dg == 0) scS[r][cand] = s;
    }
  }

  // per-row final top-4 + softmax (lanes 0..15 = wave's 16 rows)
  if (l < 16) {
    int r = w * 16 + l;
    float s0 = NEG_INF, s1 = NEG_INF, s2 = NEG_INF, s3 = NEG_INF;
    int i0 = 0, i1 = 0, i2 = 0, i3 = 0;
#pragma unroll
    for (int c8 = 0; c8 < 8; ++c8)
      insert4(scS[r][c8], (int)(kLp[r][c8] & 1023u), s0, s1, s2, s3, i0, i1,
              i2, i3);
    float m = s0;
    float e0 = expf(s0 - m), e1 = expf(s1 - m);
    float e2 = expf(s2 - m), e3 = expf(s3 - m);
    float inv = 1.f / (e0 + e1 + e2 + e3);
    wgt[r][0] = e0 * inv; wgt[r][1] = e1 * inv;
    wgt[r][2] = e2 * inv; wgt[r][3] = e3 * inv;
    widx[r][0] = i0; widx[r][1] = i1; widx[r][2] = i2; widx[r][3] = i3;
  }

  // ---- Stage C: lane = d; gather V, weight, multiply q, accumulate rows
  const float* vbh = vg + (size_t)bhbase;
  float acc = 0.f;
#pragma unroll 4
  for (int rr = 0; rr < 16; ++rr) {
    int r = w * 16 + rr;
    float w0 = wgt[r][0], w1 = wgt[r][1], w2 = wgt[r][2], w3 = wgt[r][3];
    int x0 = widx[r][0], x1 = widx[r][1], x2 = widx[r][2], x3 = widx[r][3];
    float wv = w0 * vbh[(size_t)x0 * 64 + l];
    wv = fmaf(w1, vbh[(size_t)x1 * 64 + l], wv);
    wv = fmaf(w2, vbh[(size_t)x2 * 64 + l], wv);
    wv = fmaf(w3, vbh[(size_t)x3 * 64 + l], wv);
    acc = fmaf(wv, qf[bhbase + (rg * 128 + r) * 64 + l], acc);
  }
  atomicAdd(&out[(bh >> 3) * Cc + l * Hc + (bh & 7)], acc);
}

// ---------------------------------------------------------------- launch
extern "C" void kernel_launch(void* const* d_in, const int* in_sizes, int n_in,
                              void* d_out, int out_size, void* d_ws,
                              size_t ws_size, hipStream_t stream) {
  (void)in_sizes; (void)n_in; (void)out_size; (void)ws_size;
  const float* x = (const float*)d_in[0];
  const float* wq = (const float*)d_in[1];
  const float* bias = (const float*)d_in[2];
  float* out = (float*)d_out;

  float* vbuf = (float*)d_ws;               // QSZ f32  (16.8 MB)
  float* kf = vbuf + QSZ;                   // QSZ f32  (16.8 MB)
  float* qf = kf + QSZ;                     // QSZ f32  (16.8 MB)
  ushort_t* khi = (ushort_t*)(qf + QSZ);    // QSZ bf16 (8.4 MB)
  ushort_t* qhi = khi + QSZ;                // QSZ bf16 (8.4 MB)
  ushort_t* xth = qhi + QSZ;                // XTSZ bf16 (8.4 MB)
  ushort_t* wth = xth + XTSZ;               // WTSZ bf16 (1.6 MB)
  ushort_t* wtl = wth + WTSZ;               // WTSZ bf16 (1.6 MB)

  conv_x<<<dim3(16, 8, 8), 256, 0, stream>>>(x, xth, out);
  conv_w<<<dim3(24, 8), 256, 0, stream>>>(wq, wth, wtl);
  qkv_gemm_mfma<<<dim3(64, 12), 256, 0, stream>>>(xth, wth, wtl, bias, vbuf,
                                                  kf, qf, khi, qhi);
  attn_topk_mfma<<<dim3(512), 512, 0, stream>>>(khi, qhi, kf, qf, vbuf, out);
}